// Round 10
// baseline (187.065 us; speedup 1.0000x reference)
//
#include <hip/hip_runtime.h>

// RoutingAttention gfx950 — R10.
// proj/oproj: full-N blocks (X/ctx read ONCE), full 128KB W staged via async
// global_load_lds (dynamic LDS), coalesced 64B+ epilogue stores (fp32 out as
// contiguous 1KB wave lines). attn: depth-2 K/V prefetch.
// B=2 P=8 S=1024 C=256 NH=8 DK=32; T=16384; NW=128.

typedef _Float16 half8 __attribute__((ext_vector_type(8)));
typedef _Float16 half4 __attribute__((ext_vector_type(4)));
typedef float f32x4 __attribute__((ext_vector_type(4)));

#if __has_builtin(__builtin_amdgcn_exp2f)
#define EXP2F(x) __builtin_amdgcn_exp2f(x)
#else
#define EXP2F(x) exp2f(x)
#endif

__device__ __forceinline__ f32x4 mfma16(half8 a, half8 b, f32x4 c) {
  return __builtin_amdgcn_mfma_f32_16x16x32_f16(a, b, c, 0, 0, 0);
}

__device__ __forceinline__ int pk2(float a, float b) {
  auto h = __builtin_amdgcn_cvt_pkrtz(a, b);
  return __builtin_bit_cast(int, h);
}

__device__ __forceinline__ half8 cvt8(float4 f0, float4 f1) {
  union { int i[4]; half8 h; } u;
  u.i[0] = pk2(f0.x, f0.y); u.i[1] = pk2(f0.z, f0.w);
  u.i[2] = pk2(f1.x, f1.y); u.i[3] = pk2(f1.z, f1.w);
  return u.h;
}

// async global->LDS, 16B per lane; lds dest = wave-uniform base + lane*16
__device__ __forceinline__ void g2lds16(const _Float16* g, _Float16* l) {
  __builtin_amdgcn_global_load_lds(
      (const __attribute__((address_space(1))) void*)g,
      (__attribute__((address_space(3))) void*)l, 16, 0, 0);
}

// ws layout (halves)
static constexpr size_t QH_OFF  = 0;          // (win,s,dk), q scaled log2(e)/sqrt(32)
static constexpr size_t KH_OFF  = 4194304;    // (win,s,dk)
static constexpr size_t VT_OFF  = 8388608;    // (win,dk,s)
static constexpr size_t CTX_OFF = 12582912;   // (tok,C)
static constexpr size_t WF_OFF  = 16777216;   // 4 mats frag-contiguous fp16

// ---------------- W prep: fp32 -> fp16 frag-contiguous ----------------
// WF[mat][ntg][ks][lane][j] = W[ntg*16+(lane&15)][ks*32+(lane>>4)*8+j]
__global__ __launch_bounds__(256) void prep_kernel(
    const float* __restrict__ wq, const float* __restrict__ wk,
    const float* __restrict__ wv, const float* __restrict__ wo,
    _Float16* __restrict__ ws)
{
  int u = blockIdx.x * 256 + threadIdx.x;          // 0..32767
  int lane = u & 63, ks = (u >> 6) & 7, nt = (u >> 9) & 15, mat = u >> 13;
  const float* W = (mat == 0) ? wq : (mat == 1) ? wk : (mat == 2) ? wv : wo;
  const float* p = W + (size_t)(nt * 16 + (lane & 15)) * 256 + ks * 32 + (lane >> 4) * 8;
  half8 h = cvt8(*(const float4*)p, *(const float4*)(p + 4));
  *(half8*)(ws + WF_OFF + (size_t)u * 8) = h;
}

// ---------------- Q/K/V projection: Y = X @ W^T + b -------------------------
// Block 32m x 256n (FULL N -> X read once). 4 waves, wave = 32m x 64n
// (2mt x 4nt, ntg = wid*4+t). Full 128KB W mat async-staged; LDS reused for
// the coalesced store-transpose epilogue. Grid (512, 3); 1 WG/CU (LDS-capped).
__global__ __launch_bounds__(256, 1) void proj_kernel(
    const float* __restrict__ xq, const float* __restrict__ xk, const float* __restrict__ xv,
    const float* __restrict__ bq, const float* __restrict__ bk, const float* __restrict__ bv,
    _Float16* __restrict__ ws)
{
  extern __shared__ __align__(16) _Float16 Wb[];   // 128KB dynamic

  int mode = blockIdx.y;
  const float* X  = (mode == 0) ? xq : (mode == 1) ? xk : xv;
  const float* bias = (mode == 0) ? bq : (mode == 1) ? bk : bv;
  const _Float16* WFs = ws + WF_OFF + (size_t)mode * 65536;   // full mat
  _Float16* outp = ws + ((mode == 0) ? QH_OFF : (mode == 1) ? KH_OFF : VT_OFF);
  const float scale = (mode == 0) ? 0.2550348654f : 1.0f;  // log2(e)/sqrt(32)

  int tid = threadIdx.x, lane = tid & 63, wid = tid >> 6;
  int l16 = lane & 15, quad = lane >> 4;
  int m0 = blockIdx.x * 32;

  // ---- A: all 32 fp32 float4 loads upfront (rows m0+l16, m0+16+l16) ----
  const float* r0 = X + (size_t)(m0 + l16) * 256 + quad * 8;
  const float* r1 = r0 + 16 * 256;
  float4 a0[8][2], a1[8][2];
#pragma unroll
  for (int ks = 0; ks < 8; ++ks) {
    a0[ks][0] = *(const float4*)(r0 + ks * 32);
    a0[ks][1] = *(const float4*)(r0 + ks * 32 + 4);
    a1[ks][0] = *(const float4*)(r1 + ks * 32);
    a1[ks][1] = *(const float4*)(r1 + ks * 32 + 4);
  }
  // ---- B: async stage full 128KB (32 instr/wave, contiguous) ----
#pragma unroll
  for (int i = 0; i < 32; ++i) {
    int off = wid * 16384 + i * 512;     // halves
    g2lds16(WFs + off + lane * 8, Wb + off);
  }

  half8 a16[2][8];
#pragma unroll
  for (int ks = 0; ks < 8; ++ks) {
    a16[0][ks] = cvt8(a0[ks][0], a0[ks][1]);
    a16[1][ks] = cvt8(a1[ks][0], a1[ks][1]);
  }
  f32x4 acc[2][4] = {};
  __syncthreads();

#pragma unroll
  for (int ks = 0; ks < 8; ++ks) {
    half8 bf[4];
#pragma unroll
    for (int t = 0; t < 4; ++t)
      bf[t] = *(const half8*)(Wb + ((size_t)((wid * 4 + t) * 8 + ks) * 512) + lane * 8);
#pragma unroll
    for (int mt = 0; mt < 2; ++mt)
#pragma unroll
      for (int t = 0; t < 4; ++t)
        acc[mt][t] = mfma16(a16[mt][ks], bf[t], acc[mt][t]);
  }

  __syncthreads();                       // Wb dead; reuse for transpose
  int b = m0 >> 13, p = (m0 >> 10) & 7, s0 = m0 & 1023;
  if (mode < 2) {
    _Float16* Lt = Wb;                   // [32][264]
#pragma unroll
    for (int mt = 0; mt < 2; ++mt)
#pragma unroll
      for (int t = 0; t < 4; ++t) {
        int ncol = wid * 64 + t * 16 + l16;
        float bval = bias[ncol];
#pragma unroll
        for (int r = 0; r < 4; ++r)
          Lt[(mt * 16 + quad * 4 + r) * 264 + ncol] =
              (_Float16)((acc[mt][t][r] + bval) * scale);
      }
    __syncthreads();
    // 256 segs (32 s x 8 h) x 4 pieces of 16B; 4 lanes/seg -> 64B contiguous
#pragma unroll
    for (int j = 0; j < 4; ++j) {
      int seg = j * 64 + (tid >> 2), piece = tid & 3;
      int s = seg & 31, h = seg >> 5;
      half8 v = *(const half8*)(Lt + s * 264 + h * 32 + piece * 8);
      size_t wbase = (size_t)((b * 8 + h) * 8 + p) * 32768;
      *(half8*)(outp + wbase + (size_t)(s0 + s) * 32 + piece * 8) = v;
    }
  } else {
    _Float16* Lt = Wb;                   // [256][40]
#pragma unroll
    for (int mt = 0; mt < 2; ++mt)
#pragma unroll
      for (int t = 0; t < 4; ++t) {
        int ncol = wid * 64 + t * 16 + l16;
        float bval = bias[ncol];
        half4 h4;
#pragma unroll
        for (int r = 0; r < 4; ++r) h4[r] = (_Float16)(acc[mt][t][r] + bval);
        *(half4*)(Lt + ncol * 40 + mt * 16 + quad * 4) = h4;
      }
    __syncthreads();
    // 256 dk-rows x 4 pieces of 16B; 4 lanes/row -> 64B contiguous
#pragma unroll
    for (int j = 0; j < 4; ++j) {
      int o = j * 64 + (tid >> 2), piece = tid & 3;
      int h = o >> 5, dki = o & 31;
      half8 v = *(const half8*)(Lt + o * 40 + piece * 8);
      size_t wbase = (size_t)((b * 8 + h) * 8 + p) * 32768;
      *(half8*)(outp + wbase + (size_t)dki * 1024 + s0 + piece * 8) = v;
    }
  }
}

// ---------------- attention: wave split-K, exp2-direct, depth-2 prefetch ----
__global__ __launch_bounds__(256, 3) void attn_kernel(
    const _Float16* __restrict__ ws, _Float16* __restrict__ ctx)
{
  __shared__ __align__(16) unsigned char smem[20480];
  _Float16* Pb = (_Float16*)smem;                  // in-loop: [4][64][40] fp16

  int tid = threadIdx.x, lane = tid & 63, wid = tid >> 6;
  int l16 = lane & 15, quad = lane >> 4;
  int w = blockIdx.x & 127, qc = blockIdx.x >> 7;  // XCD-clustered; qc 0..15
  int b = w >> 6, h = (w >> 3) & 7, p = w & 7;
  const _Float16* qhw = ws + QH_OFF + (size_t)w * 32768;
  const _Float16* khw = ws + KH_OFF + (size_t)w * 32768;
  const _Float16* vtw = ws + VT_OFF + (size_t)w * 32768;
  int qrow0 = qc * 64;

  half8 qf[4];
#pragma unroll
  for (int g = 0; g < 4; ++g)
    qf[g] = *(const half8*)(qhw + (size_t)(qrow0 + g * 16 + l16) * 32 + quad * 8);

  half8 ones = {};
  if (l16 == 0) {
#pragma unroll
    for (int j = 0; j < 8; ++j) ones[j] = (_Float16)1.0f;
  }

  f32x4 Ot[2][4] = {};      // [dk-tile][q-group] O^T partials
  f32x4 Lacc[4] = {};       // lsum via ones-row MFMA
  _Float16* Pw = Pb + wid * 2560;
  int kbase = wid * 256;

  // depth-2 rolling K/V pipeline
  half8 kA0 = *(const half8*)(khw + (size_t)(kbase + l16) * 32 + quad * 8);
  half8 kA1 = *(const half8*)(khw + (size_t)(kbase + 16 + l16) * 32 + quad * 8);
  half8 vA0 = *(const half8*)(vtw + (size_t)l16 * 1024 + kbase + quad * 8);
  half8 vA1 = *(const half8*)(vtw + (size_t)(16 + l16) * 1024 + kbase + quad * 8);
  int kc1 = kbase + 32;
  half8 kB0 = *(const half8*)(khw + (size_t)(kc1 + l16) * 32 + quad * 8);
  half8 kB1 = *(const half8*)(khw + (size_t)(kc1 + 16 + l16) * 32 + quad * 8);
  half8 vB0 = *(const half8*)(vtw + (size_t)l16 * 1024 + kc1 + quad * 8);
  half8 vB1 = *(const half8*)(vtw + (size_t)(16 + l16) * 1024 + kc1 + quad * 8);

  for (int kk = 0; kk < 8; ++kk) {
    int k2 = kbase + (((kk + 2) & 7) << 5);
    half8 kC0 = *(const half8*)(khw + (size_t)(k2 + l16) * 32 + quad * 8);
    half8 kC1 = *(const half8*)(khw + (size_t)(k2 + 16 + l16) * 32 + quad * 8);
    half8 vC0 = *(const half8*)(vtw + (size_t)l16 * 1024 + k2 + quad * 8);
    half8 vC1 = *(const half8*)(vtw + (size_t)(16 + l16) * 1024 + k2 + quad * 8);

    f32x4 z = {0.f, 0.f, 0.f, 0.f};
    f32x4 St0[4], St1[4];
#pragma unroll
    for (int g = 0; g < 4; ++g) St0[g] = mfma16(kA0, qf[g], z);
#pragma unroll
    for (int g = 0; g < 4; ++g) St1[g] = mfma16(kA1, qf[g], z);

#pragma unroll
    for (int g = 0; g < 4; ++g) {
      f32x4 pv;
#pragma unroll
      for (int r = 0; r < 4; ++r) pv[r] = EXP2F(St0[g][r]);
      union { int i[2]; half4 hh; } uu;
      uu.i[0] = pk2(pv[0], pv[1]); uu.i[1] = pk2(pv[2], pv[3]);
      *(half4*)(Pw + (g * 16 + l16) * 40 + quad * 4) = uu.hh;
    }
#pragma unroll
    for (int g = 0; g < 4; ++g) {
      f32x4 pv;
#pragma unroll
      for (int r = 0; r < 4; ++r) pv[r] = EXP2F(St1[g][r]);
      union { int i[2]; half4 hh; } uu;
      uu.i[0] = pk2(pv[0], pv[1]); uu.i[1] = pk2(pv[2], pv[3]);
      *(half4*)(Pw + (g * 16 + l16) * 40 + 16 + quad * 4) = uu.hh;
    }

#pragma unroll
    for (int g = 0; g < 4; ++g) {
      half8 pf = *(const half8*)(Pw + (g * 16 + l16) * 40 + quad * 8);
      Ot[0][g] = mfma16(vA0, pf, Ot[0][g]);
      Ot[1][g] = mfma16(vA1, pf, Ot[1][g]);
      Lacc[g]  = mfma16(ones, pf, Lacc[g]);
    }
    kA0 = kB0; kA1 = kB1; vA0 = vB0; vA1 = vB1;
    kB0 = kC0; kB1 = kC1; vB0 = vC0; vB1 = vC1;
  }

  // ---- cross-wave merge (reuse smem as fp16 Of + fp32 Ls) ----
  __syncthreads();
  unsigned int* Of16 = (unsigned int*)smem;        // [4][64][17] u32 (fp16x2)
  float* Ls = (float*)(smem + 17408);              // [4][64]
  if (quad == 0) {
#pragma unroll
    for (int g = 0; g < 4; ++g) Ls[wid * 64 + g * 16 + l16] = Lacc[g][0];
  }
#pragma unroll
  for (int d = 0; d < 2; ++d)
#pragma unroll
    for (int g = 0; g < 4; ++g) {
      int base = wid * 1088 + (g * 16 + l16) * 17 + d * 8 + quad * 2;
      Of16[base]     = pk2(Ot[d][g][0], Ot[d][g][1]);
      Of16[base + 1] = pk2(Ot[d][g][2], Ot[d][g][3]);
    }
  __syncthreads();

  int q = tid >> 2, c = tid & 3;
  float lt = Ls[q] + Ls[64 + q] + Ls[128 + q] + Ls[192 + q];
  float linv = 1.0f / lt;
  union { int i[4]; half8 hh; } u;
#pragma unroll
  for (int jj = 0; jj < 4; ++jj) {
    int idx = q * 17 + c * 4 + jj;
    float sa = 0.f, sb = 0.f;
#pragma unroll
    for (int ww = 0; ww < 4; ++ww) {
      union { unsigned int x; _Float16 h2[2]; } cv;
      cv.x = Of16[ww * 1088 + idx];
      sa += (float)cv.h2[0]; sb += (float)cv.h2[1];
    }
    u.i[jj] = pk2(sa * linv, sb * linv);
  }
  size_t tok = (size_t)(b * 8 + p) * 1024 + qrow0 + q;
  *(half8*)(ctx + tok * 256 + h * 32 + c * 8) = u.hh;
}

// ---------------- output projection: out = ctx @ Wo^T + bo (fp32) -----------
// Block 32m x 256n (FULL N -> ctx read once). Full 128KB Wo staged; LDS reused
// as fp32 [32][260] transpose -> out written as contiguous 1KB wave lines.
__global__ __launch_bounds__(256, 1) void oproj_kernel(
    const _Float16* __restrict__ ws, const float* __restrict__ bo,
    float* __restrict__ out)
{
  extern __shared__ __align__(16) _Float16 Wb[];   // 128KB dynamic

  int tid = threadIdx.x, lane = tid & 63, wid = tid >> 6;
  int l16 = lane & 15, quad = lane >> 4;
  int m0 = blockIdx.x * 32;
  const _Float16* A = ws + CTX_OFF;
  const _Float16* WFs = ws + WF_OFF + 3 * (size_t)65536;

  const _Float16* r0 = A + (size_t)(m0 + l16) * 256 + quad * 8;
  const _Float16* r1 = r0 + 16 * 256;
  half8 a16[2][8];
#pragma unroll
  for (int ks = 0; ks < 8; ++ks) {
    a16[0][ks] = *(const half8*)(r0 + ks * 32);
    a16[1][ks] = *(const half8*)(r1 + ks * 32);
  }
#pragma unroll
  for (int i = 0; i < 32; ++i) {
    int off = wid * 16384 + i * 512;
    g2lds16(WFs + off + lane * 8, Wb + off);
  }
  f32x4 acc[2][4] = {};
  __syncthreads();

#pragma unroll
  for (int ks = 0; ks < 8; ++ks) {
    half8 bf[4];
#pragma unroll
    for (int t = 0; t < 4; ++t)
      bf[t] = *(const half8*)(Wb + ((size_t)((wid * 4 + t) * 8 + ks) * 512) + lane * 8);
#pragma unroll
    for (int mt = 0; mt < 2; ++mt)
#pragma unroll
      for (int t = 0; t < 4; ++t)
        acc[mt][t] = mfma16(a16[mt][ks], bf[t], acc[mt][t]);
  }

  __syncthreads();                       // Wb dead; reuse as fp32 transpose
  float* Lt = (float*)Wb;                // [32][260]
#pragma unroll
  for (int mt = 0; mt < 2; ++mt)
#pragma unroll
    for (int t = 0; t < 4; ++t) {
      int o = wid * 64 + t * 16 + l16;
      float bval = bo[o];
#pragma unroll
      for (int r = 0; r < 4; ++r)
        Lt[(mt * 16 + quad * 4 + r) * 260 + o] = acc[mt][t][r] + bval;
    }
  __syncthreads();
#pragma unroll
  for (int i = 0; i < 8; ++i) {
    int row = i * 4 + (tid >> 6), piece = tid & 63;
    float4 v = *(const float4*)(Lt + row * 260 + piece * 4);
    *(float4*)(out + (size_t)(m0 + row) * 256 + piece * 4) = v;
  }
}

extern "C" void kernel_launch(void* const* d_in, const int* in_sizes, int n_in,
                              void* d_out, int out_size, void* d_ws, size_t ws_size,
                              hipStream_t stream)
{
  const float* q  = (const float*)d_in[0];
  const float* k  = (const float*)d_in[1];
  const float* v  = (const float*)d_in[2];
  const float* Wq = (const float*)d_in[3];
  const float* bq = (const float*)d_in[4];
  const float* Wk = (const float*)d_in[5];
  const float* bk = (const float*)d_in[6];
  const float* Wv = (const float*)d_in[7];
  const float* bv = (const float*)d_in[8];
  const float* Wo = (const float*)d_in[9];
  const float* bo = (const float*)d_in[10];
  _Float16* ws = (_Float16*)d_ws;
  float* out = (float*)d_out;

  prep_kernel<<<128, 256, 0, stream>>>(Wq, Wk, Wv, Wo, ws);
  proj_kernel<<<dim3(512, 3), 256, 131072, stream>>>(q, k, v, bq, bk, bv, ws);
  attn_kernel<<<2048, 256, 0, stream>>>(ws, ws + CTX_OFF);
  oproj_kernel<<<512, 256, 131072, stream>>>(ws, bo, out);
}